// Round 7
// baseline (26.918 us; speedup 1.0000x reference)
//
#include <hip/hip_runtime.h>
#include <math.h>

// Reranker tie-aware RankNet loss — R7 (single fused kernel, lean loop).
// B=4096 rows, n=64. One 64-lane wave per row; 1024 blocks x 256 threads.
//   - group-end e via one __ballot + ctz;  mask (b > e);  cnt = 63-e analytic
//   - softplus base-2 log-of-product: per pair ONE v_exp_f32, no per-pair log
//       sum softplus(t)/ln2 = sum max(t,0) + log2( prod (1 + masked 2^-|t|) )
//     8 chains x 8 factors, each factor in (1,2] -> chain <= 2^8 (no overflow)
//   - finalize fused: ticket atomic (agent scope); block drawing residue nb-1
//     reduces all 1024 partials in FIXED order -> deterministic, poison-proof.
// Removes one graph node vs the 2-kernel version (launch-overhead dominated).

#define N 64
#define WPB 4                   // waves (rows) per 256-thread block
#define LN2 0.6931471805599453f
#define LOG2E 1.4426950408889634f

__device__ __forceinline__ float readlane_f(float v, int srclane) {
    return __int_as_float(__builtin_amdgcn_readlane(__float_as_int(v), srclane));
}

#define TERM(i, p, r) do {                                         \
    const int b_ = bb + (i);                                       \
    float t_  = readlane_f(pa2, b_) - pa2;                         \
    float g_  = __builtin_amdgcn_exp2f(-fabsf(t_));                \
    bool  m_  = b_ > e;                                            \
    float gm_ = m_ ? g_ : 0.0f;                                    \
    p = fmaf(gm_, p, p);              /* p *= (1 + masked g) */    \
    r += m_ ? fmaxf(t_, 0.0f) : 0.0f;                              \
} while (0)

__global__ __launch_bounds__(256) void rank_loss_fused(
    const float* __restrict__ logits, const int* __restrict__ kd,
    float* __restrict__ out, float* __restrict__ partials,
    unsigned* __restrict__ ticket, int B, int nb)
{
    const int lane = threadIdx.x & 63;
    const int wave = threadIdx.x >> 6;
    const int row  = blockIdx.x * WPB + wave;

    float p0=1.f,p1=1.f,p2=1.f,p3=1.f,p4=1.f,p5=1.f,p6=1.f,p7=1.f;
    float r0=0.f,r1=0.f,r2=0.f,r3=0.f,r4=0.f,r5=0.f,r6=0.f,r7=0.f;
    float cnt = 0.f, psum = 0.f;

    if (row < B) {
        const int base = row * N + lane;
        const int   k   = kd[base];
        const float pa2 = logits[base] * LOG2E;

        // group-end lane e: smallest j >= lane with (j==63 or k[j]!=k[j+1])
        const int knext = __shfl_down(k, 1);
        unsigned long long endm = __ballot(lane == 63 || k != knext);
        const int e = lane + __builtin_ctzll(endm >> lane);   // bit 63 set
        cnt = (float)(63 - e);

        #pragma unroll 1
        for (int bb = 0; bb < N; bb += 8) {
            TERM(0, p0, r0); TERM(1, p1, r1); TERM(2, p2, r2); TERM(3, p3, r3);
            TERM(4, p4, r4); TERM(5, p5, r5); TERM(6, p6, r6); TERM(7, p7, r7);
        }

        float prod = ((p0 * p1) * (p2 * p3)) * ((p4 * p5) * (p6 * p7));
        float rsum = ((r0 + r1) + (r2 + r3)) + ((r4 + r5) + (r6 + r7));
        psum = rsum + __builtin_amdgcn_logf(prod);   // v_log_f32 == log2
    }

    #pragma unroll
    for (int off = 32; off; off >>= 1) {
        psum += __shfl_down(psum, off);
        cnt  += __shfl_down(cnt,  off);
    }

    __shared__ float ssum[WPB], scnt[WPB];
    __shared__ int lastFlag;
    if (lane == 0) { ssum[wave] = psum; scnt[wave] = cnt; }
    __syncthreads();

    if (threadIdx.x == 0) {
        float s = 0.f, c = 0.f;
        #pragma unroll
        for (int w = 0; w < WPB; ++w) { s += ssum[w]; c += scnt[w]; }
        __hip_atomic_store(&partials[2 * blockIdx.x + 0], s,
                           __ATOMIC_RELAXED, __HIP_MEMORY_SCOPE_AGENT);
        __hip_atomic_store(&partials[2 * blockIdx.x + 1], c,
                           __ATOMIC_RELAXED, __HIP_MEMORY_SCOPE_AGENT);
        unsigned t = __hip_atomic_fetch_add(ticket, 1u,
                           __ATOMIC_ACQ_REL, __HIP_MEMORY_SCOPE_AGENT);
        // exactly one of any nb consecutive tickets == nb-1 (mod nb):
        // correct for any poisoned starting value of *ticket.
        lastFlag = ((t % (unsigned)nb) == (unsigned)(nb - 1)) ? 1 : 0;
    }
    __syncthreads();

    if (lastFlag) {               // last-arriving block: fixed-order finalize
        const int t = threadIdx.x;
        float s = 0.f, c = 0.f;
        #pragma unroll
        for (int j = 0; j < 4; ++j) {          // nb = 1024 = 4 * 256, in order
            int i = j * 256 + t;
            s += __hip_atomic_load(&partials[2 * i + 0],
                                   __ATOMIC_RELAXED, __HIP_MEMORY_SCOPE_AGENT);
            c += __hip_atomic_load(&partials[2 * i + 1],
                                   __ATOMIC_RELAXED, __HIP_MEMORY_SCOPE_AGENT);
        }
        #pragma unroll
        for (int off = 32; off; off >>= 1) {
            s += __shfl_down(s, off);
            c += __shfl_down(c, off);
        }
        __shared__ float fs[WPB], fc[WPB];
        if (lane == 0) { fs[wave] = s; fc[wave] = c; }
        __syncthreads();
        if (t == 0) {
            float S = 0.f, C = 0.f;
            #pragma unroll
            for (int w = 0; w < WPB; ++w) { S += fs[w]; C += fc[w]; }
            out[0] = S * LN2 / C;
        }
    }
}

extern "C" void kernel_launch(void* const* d_in, const int* in_sizes, int n_in,
                              void* d_out, int out_size, void* d_ws, size_t ws_size,
                              hipStream_t stream) {
    const float* logits = (const float*)d_in[0];
    const int*   kd     = (const int*)d_in[1];
    float*       out    = (float*)d_out;
    const int B  = in_sizes[1] / N;                 // 4096
    const int nb = B / WPB;                         // 1024 blocks

    float*    partials = (float*)d_ws;              // 2*nb floats = 8 KiB
    unsigned* ticket   = (unsigned*)((char*)d_ws + 8192);

    rank_loss_fused<<<nb, 256, 0, stream>>>(logits, kd, out, partials,
                                            ticket, B, nb);
}